// Round 6
// baseline (273.190 us; speedup 1.0000x reference)
//
#include <hip/hip_runtime.h>
#include <hip/hip_bf16.h>

// B=2, S=2048, D_MODEL=1024, H=16, D_HEAD=64.
// I/O fp32; mask int32 (nonzero = masked). Internals bf16 MFMA.
// R16: attn PV restructured to mfma_f32_16x16x16_bf16 consuming P in its
// NATIVE post-QK^T register layout (lane(lr,lg) holds P^T[16ni+4lg+r][lr];
// K=16 B-operand wants col=lr,k=4lg+j -> exact match). Deletes the entire
// permlane32/16 butterfly + tied-operand moves from R15. V read as b64
// slices; rowsum via K=16 ones-MFMA. gemms/prep unchanged from R15.

typedef __bf16 bf16x8 __attribute__((ext_vector_type(8)));
typedef __bf16 bf16x4 __attribute__((ext_vector_type(4)));
typedef short short4v __attribute__((ext_vector_type(4)));
typedef float f32x4 __attribute__((ext_vector_type(4)));

#define S_LEN 2048
#define DM 1024
#define NH 16
#define DH 64
#define MROWS 4096  // B*S

// 0.125 * log2(e): folds the 1/sqrt(DH) scale AND the exp->exp2 base change
// into the Q projection (applied in f32 before the single bf16 rounding).
#define QSCALE 0.18033688011112042f

static __device__ __forceinline__ unsigned short f2bf(float f) {
    __bf16 b = (__bf16)f;
    unsigned short u; __builtin_memcpy(&u, &b, 2); return u;
}

static __device__ __forceinline__ float exp2_hw(float x) {
#if __has_builtin(__builtin_amdgcn_exp2f)
    return __builtin_amdgcn_exp2f(x);
#else
    float r; asm("v_exp_f32 %0, %1" : "=v"(r) : "v"(x)); return r;
#endif
}

// K=16 bf16 MFMA wrapper (builtin name differs across ROCm versions).
static __device__ __forceinline__ f32x4 mfma16(bf16x4 a, bf16x4 b, f32x4 c) {
#if __has_builtin(__builtin_amdgcn_mfma_f32_16x16x16_bf16)
    return __builtin_amdgcn_mfma_f32_16x16x16_bf16(a, b, c, 0, 0, 0);
#elif __has_builtin(__builtin_amdgcn_mfma_f32_16x16x16bf16_1k)
    short4v as, bs;
    __builtin_memcpy(&as, &a, 8);
    __builtin_memcpy(&bs, &b, 8);
    return __builtin_amdgcn_mfma_f32_16x16x16bf16_1k(as, bs, c, 0, 0, 0);
#else
    asm("v_mfma_f32_16x16x16_bf16 %0, %1, %2, %0" : "+v"(c) : "v"(a), "v"(b));
    return c;
#endif
}

static __device__ __forceinline__ bf16x8 cvt8(float4 a, float4 b) {
    bf16x8 o;
    o[0] = (__bf16)a.x; o[1] = (__bf16)a.y; o[2] = (__bf16)a.z; o[3] = (__bf16)a.w;
    o[4] = (__bf16)b.x; o[5] = (__bf16)b.y; o[6] = (__bf16)b.z; o[7] = (__bf16)b.w;
    return o;
}

// Fused prep: mask bit-pack + 3 X cvts + 4 W cvts in one launch.
__global__ __launch_bounds__(256)
void prep(const int* __restrict__ m, unsigned* __restrict__ mb,
          const float* __restrict__ Q, unsigned short* __restrict__ dQ,
          const float* __restrict__ K, unsigned short* __restrict__ dK,
          const float* __restrict__ V, unsigned short* __restrict__ dV,
          const float* __restrict__ W0, unsigned short* __restrict__ dW0,
          const float* __restrict__ W1, unsigned short* __restrict__ dW1,
          const float* __restrict__ W2, unsigned short* __restrict__ dW2,
          const float* __restrict__ W3, unsigned short* __restrict__ dW3)
{
    const int bx = blockIdx.x, tid = threadIdx.x;
    if (bx < 1024) {
        const int lane = tid & 63, w = tid >> 6;
        const int row = bx * 4 + w;
        const int* src = m + (size_t)row * S_LEN;
        unsigned* dst = mb + (size_t)row * (S_LEN / 32);
        for (int i = 0; i < 32; i++) {
            int v = src[i * 64 + lane];
            unsigned long long bm = __ballot(v != 0);
            if (lane == 0) { dst[i*2] = (unsigned)bm; dst[i*2+1] = (unsigned)(bm >> 32); }
        }
    } else if (bx < 7168) {
        int t = bx - 1024;
        int which = t >> 11;
        const float* s = which == 0 ? Q : which == 1 ? K : V;
        unsigned short* d = which == 0 ? dQ : which == 1 ? dK : dV;
        int i = ((t & 2047) * 256 + tid) * 8;
        float4 a = *(const float4*)(s + i);
        float4 b = *(const float4*)(s + i + 4);
        *(bf16x8*)(d + i) = cvt8(a, b);
    } else {
        int t = bx - 7168;
        int which = t >> 9;
        const float* s = which == 0 ? W0 : which == 1 ? W1 : which == 2 ? W2 : W3;
        unsigned short* d = which == 0 ? dW0 : which == 1 ? dW1 : which == 2 ? dW2 : dW3;
        int i = ((t & 511) * 256 + tid) * 8;
        float4 a = *(const float4*)(s + i);
        float4 b = *(const float4*)(s + i + 4);
        *(bf16x8*)(d + i) = cvt8(a, b);
    }
}

// QKV GEMM: 128x128 tile, BK=32, global_load_lds, 2-phase LDS double-buffer.
// z: 0/1 head-split (q_ws/k_ws), 2 transposed (vt_ws). z==0 pre-scales by
// QSCALE. XCD chunk swizzle: 3MB working set per XCD L2.
__global__ __launch_bounds__(256)
void gemm128(const unsigned short* __restrict__ X0, const unsigned short* __restrict__ X1,
             const unsigned short* __restrict__ X2,
             const unsigned short* __restrict__ W0, const unsigned short* __restrict__ W1,
             const unsigned short* __restrict__ W2,
             const float* __restrict__ b0, const float* __restrict__ b1,
             const float* __restrict__ b2,
             unsigned short* __restrict__ d0, unsigned short* __restrict__ d1,
             unsigned short* __restrict__ d2)
{
    __shared__ __align__(16) unsigned short As[2][128 * 32];
    __shared__ __align__(16) unsigned short Bs[2][128 * 32];

    const int bid = blockIdx.x + blockIdx.y * 8 + blockIdx.z * 256; // 0..767
    const int xcd = bid & 7;
    const int t   = bid >> 3;
    const int z   = t >> 5;
    const int u   = t & 31;
    const int nt  = u & 7;
    const int mt  = xcd * 4 + (u >> 3);

    const unsigned short* X = z == 0 ? X0 : z == 1 ? X1 : X2;
    const unsigned short* W = z == 0 ? W0 : z == 1 ? W1 : W2;
    const float* bias        = z == 0 ? b0 : z == 1 ? b1 : b2;
    unsigned short* dstb     = z == 0 ? d0 : z == 1 ? d1 : d2;

    const int tid  = threadIdx.x;
    const int m0   = mt * 128;
    const int n0   = nt * 128;
    const int lane = tid & 63;
    const int w    = tid >> 6;
    const int wm   = (w >> 1) * 64, wn = (w & 1) * 64;
    const int lr   = lane & 15;
    const int lg   = lane >> 4;

    const int srow = tid >> 2, sc8 = (tid & 3) * 8;
    const int srow1 = (tid + 256) >> 2, sc81 = ((tid + 256) & 3) * 8;

    f32x4 acc[4][4];
#pragma unroll
    for (int i = 0; i < 4; i++)
#pragma unroll
        for (int j = 0; j < 4; j++) acc[i][j] = f32x4{0.f, 0.f, 0.f, 0.f};

#define G128_STAGE(buf, kk)                                                          \
    do {                                                                             \
        __builtin_amdgcn_global_load_lds(                                            \
            (const __attribute__((address_space(1))) unsigned*)&X[(size_t)(m0 + srow) * DM + (kk) + sc8],   \
            (__attribute__((address_space(3))) unsigned*)&As[buf][tid * 8], 16, 0, 0);                      \
        __builtin_amdgcn_global_load_lds(                                            \
            (const __attribute__((address_space(1))) unsigned*)&W[(size_t)(n0 + srow) * DM + (kk) + sc8],   \
            (__attribute__((address_space(3))) unsigned*)&Bs[buf][tid * 8], 16, 0, 0);                      \
        __builtin_amdgcn_global_load_lds(                                            \
            (const __attribute__((address_space(1))) unsigned*)&X[(size_t)(m0 + srow1) * DM + (kk) + sc81], \
            (__attribute__((address_space(3))) unsigned*)&As[buf][(tid + 256) * 8], 16, 0, 0);              \
        __builtin_amdgcn_global_load_lds(                                            \
            (const __attribute__((address_space(1))) unsigned*)&W[(size_t)(n0 + srow1) * DM + (kk) + sc81], \
            (__attribute__((address_space(3))) unsigned*)&Bs[buf][(tid + 256) * 8], 16, 0, 0);              \
    } while (0)

    G128_STAGE(0, 0);
    __syncthreads();

    for (int k0 = 0; k0 < DM; k0 += 32) {
        const int cur = (k0 >> 5) & 1;
        if (k0 + 32 < DM) G128_STAGE(cur ^ 1, k0 + 32);

        bf16x8 af[4], bfr[4];
#pragma unroll
        for (int mi = 0; mi < 4; mi++)
            af[mi] = *(const bf16x8*)(&As[cur][(wm + mi * 16 + lr) * 32 + lg * 8]);
#pragma unroll
        for (int ni = 0; ni < 4; ni++)
            bfr[ni] = *(const bf16x8*)(&Bs[cur][(wn + ni * 16 + lr) * 32 + lg * 8]);
#pragma unroll
        for (int mi = 0; mi < 4; mi++)
#pragma unroll
            for (int ni = 0; ni < 4; ni++)
                acc[mi][ni] = __builtin_amdgcn_mfma_f32_16x16x32_bf16(
                    af[mi], bfr[ni], acc[mi][ni], 0, 0, 0);
        __syncthreads();
    }
#undef G128_STAGE

    // C/D layout: col = lane&15 -> n, row = (lane>>4)*4 + reg -> m.
#pragma unroll
    for (int mi = 0; mi < 4; mi++) {
#pragma unroll
        for (int ni = 0; ni < 4; ni++) {
            const int gcol = n0 + wn + ni * 16 + lr;
            const float bv = bias[gcol];
            const int grow0 = m0 + wm + mi * 16 + lg * 4;
            if (z == 2) {
                int b = grow0 >> 11, s = grow0 & (S_LEN - 1);
                int h = gcol >> 6, dh = gcol & 63;
                bf16x4 pk;
#pragma unroll
                for (int r = 0; r < 4; r++) pk[r] = (__bf16)(acc[mi][ni][r] + bv);
                size_t di = ((size_t)(b * NH + h) * DH + dh) * S_LEN + s;
                *(bf16x4*)(&dstb[di]) = pk;
            } else {
#pragma unroll
                for (int r = 0; r < 4; r++) {
                    int grow = grow0 + r;
                    float v = acc[mi][ni][r] + bv;
                    if (z == 0) v *= QSCALE;
                    int b = grow >> 11, s = grow & (S_LEN - 1);
                    int h = gcol >> 6, dh = gcol & 63;
                    dstb[((size_t)(b * NH + h) * S_LEN + s) * DH + dh] = f2bf(v);
                }
            }
        }
    }
}

// Out-projection: Y = X @ Wo^T + bo, fp32 out. 128M x 64N tiles, 512 blocks,
// 2-phase LDS double-buffer, XCD chunk swizzle.
__global__ __launch_bounds__(256, 2)
void gemm_out(const unsigned short* __restrict__ X, const unsigned short* __restrict__ W,
              const float* __restrict__ bias, float* __restrict__ dst)
{
    __shared__ __align__(16) unsigned short As[2][128 * 32];
    __shared__ __align__(16) unsigned short Bs[2][64 * 32];

    const int bid = blockIdx.x + blockIdx.y * 16; // 0..511
    const int xcd = bid & 7;
    const int u   = bid >> 3;
    const int nt  = u & 15;
    const int mt  = xcd * 4 + (u >> 4);

    const int tid  = threadIdx.x;
    const int m0   = mt * 128;
    const int n0   = nt * 64;
    const int lane = tid & 63;
    const int w    = tid >> 6;
    const int wm   = (w >> 1) * 64, wn = (w & 1) * 32;
    const int lr   = lane & 15;
    const int lg   = lane >> 4;

    const int srow = tid >> 2, sc8 = (tid & 3) * 8;
    const int srow1 = (tid + 256) >> 2, sc81 = ((tid + 256) & 3) * 8;

    f32x4 acc[4][2];
#pragma unroll
    for (int i = 0; i < 4; i++)
#pragma unroll
        for (int j = 0; j < 2; j++) acc[i][j] = f32x4{0.f, 0.f, 0.f, 0.f};

#define GOUT_STAGE(buf, kk)                                                          \
    do {                                                                             \
        __builtin_amdgcn_global_load_lds(                                            \
            (const __attribute__((address_space(1))) unsigned*)&X[(size_t)(m0 + srow) * DM + (kk) + sc8],   \
            (__attribute__((address_space(3))) unsigned*)&As[buf][tid * 8], 16, 0, 0);                      \
        __builtin_amdgcn_global_load_lds(                                            \
            (const __attribute__((address_space(1))) unsigned*)&X[(size_t)(m0 + srow1) * DM + (kk) + sc81], \
            (__attribute__((address_space(3))) unsigned*)&As[buf][(tid + 256) * 8], 16, 0, 0);              \
        __builtin_amdgcn_global_load_lds(                                            \
            (const __attribute__((address_space(1))) unsigned*)&W[(size_t)(n0 + srow) * DM + (kk) + sc8],   \
            (__attribute__((address_space(3))) unsigned*)&Bs[buf][tid * 8], 16, 0, 0);                      \
    } while (0)

    GOUT_STAGE(0, 0);
    __syncthreads();

    for (int k0 = 0; k0 < DM; k0 += 32) {
        const int cur = (k0 >> 5) & 1;
        if (k0 + 32 < DM) GOUT_STAGE(cur ^ 1, k0 + 32);

        bf16x8 af[4], bfr[2];
#pragma unroll
        for (int mi = 0; mi < 4; mi++)
            af[mi] = *(const bf16x8*)(&As[cur][(wm + mi * 16 + lr) * 32 + lg * 8]);
#pragma unroll
        for (int ni = 0; ni < 2; ni++)
            bfr[ni] = *(const bf16x8*)(&Bs[cur][(wn + ni * 16 + lr) * 32 + lg * 8]);
#pragma unroll
        for (int mi = 0; mi < 4; mi++)
#pragma unroll
            for (int ni = 0; ni < 2; ni++)
                acc[mi][ni] = __builtin_amdgcn_mfma_f32_16x16x32_bf16(
                    af[mi], bfr[ni], acc[mi][ni], 0, 0, 0);
        __syncthreads();
    }
#undef GOUT_STAGE

#pragma unroll
    for (int mi = 0; mi < 4; mi++)
#pragma unroll
        for (int ni = 0; ni < 2; ni++) {
            const int gcol = n0 + wn + ni * 16 + lr;
            const float bv = bias[gcol];
            const int grow0 = m0 + wm + mi * 16 + lg * 4;
#pragma unroll
            for (int r = 0; r < 4; r++)
                dst[(size_t)(grow0 + r) * DM + gcol] = acc[mi][ni][r] + bv;
        }
}

// Flash attention (transposed): S^T = K*Q^T, softmax rows along lanes.
// Wave owns 2 q-tiles (32 q). K/V LDS double-buffer (1 barrier/iter).
// PV via K=16 MFMA in NATIVE P layout (no transpose). Row-sum via K=16
// ones-MFMA. Grid 512 (XCD swizzle), 4 waves, 2 blocks/CU.
__global__ __launch_bounds__(256, 2)
void attn(const unsigned short* __restrict__ q_ws,
          const unsigned short* __restrict__ k_ws,
          const unsigned short* __restrict__ vt_ws,
          const unsigned* __restrict__ mbits,
          unsigned short* __restrict__ ctx)
{
    __shared__ __align__(16) unsigned short Ks[2][64 * 72];   // [kv][dh], +8 pad
    __shared__ __align__(16) unsigned short Vs[2][64 * 72];   // [dh][kv], +8 pad
    const int tid = threadIdx.x, lane = tid & 63, w = tid >> 6;
    const int lr = lane & 15, lg = lane >> 4;

    const int i    = blockIdx.x;            // 0..511
    const int xcd  = i & 7;
    const int slot = i >> 3;                // 0..63
    const int bh   = xcd * 4 + (slot >> 4); // 4 bh per XCD (K/V L2-resident)
    const int qblk = slot & 15;
    const int b  = bh >> 4;
    const int h  = bh & 15;
    const int q0 = qblk * 128 + w * 32;
    const int qA = q0 + lr;
    const int qB = q0 + 16 + lr;

    const int srow = tid >> 3;   // staging row
    const int sseg = tid & 7;    // 16B segment

    const unsigned short* qh = q_ws + (size_t)bh * S_LEN * DH;
    const unsigned short* kh = k_ws + (size_t)bh * S_LEN * DH;
    const unsigned short* vh = vt_ws + (size_t)bh * DH * S_LEN;
    const unsigned* mrA = mbits + (size_t)(b * S_LEN + qA) * (S_LEN / 32);
    const unsigned* mrB = mbits + (size_t)(b * S_LEN + qB) * (S_LEN / 32);

    // Q fragments (B operand of K*Q^T): Q[q][dh = c*32 + lg*8 + j].
    bf16x8 aqA[2], aqB[2];
#pragma unroll
    for (int c = 0; c < 2; c++) {
        aqA[c] = *(const bf16x8*)(&qh[(size_t)qA * DH + c * 32 + lg * 8]);
        aqB[c] = *(const bf16x8*)(&qh[(size_t)qB * DH + c * 32 + lg * 8]);
    }

    bf16x4 ones4;
#pragma unroll
    for (int j = 0; j < 4; j++) ones4[j] = (__bf16)1.0f;

    f32x4 accA[4], accB[4], accRA, accRB;
#pragma unroll
    for (int di = 0; di < 4; di++) {
        accA[di] = f32x4{0.f, 0.f, 0.f, 0.f};
        accB[di] = f32x4{0.f, 0.f, 0.f, 0.f};
    }
    accRA = f32x4{0.f, 0.f, 0.f, 0.f};
    accRB = f32x4{0.f, 0.f, 0.f, 0.f};

    // Prologue: tile 0 -> Ks[0]/Vs[0]; tile 1 -> staging regs.
    uint4 kreg0, kreg1, vreg0, vreg1;
    kreg0 = *(const uint4*)(&kh[(size_t)(srow)      * DH + sseg * 8]);
    kreg1 = *(const uint4*)(&kh[(size_t)(srow + 32) * DH + sseg * 8]);
    vreg0 = *(const uint4*)(&vh[(size_t)(srow)      * S_LEN + sseg * 8]);
    vreg1 = *(const uint4*)(&vh[(size_t)(srow + 32) * S_LEN + sseg * 8]);
    *(uint4*)(&Ks[0][(srow)      * 72 + sseg * 8]) = kreg0;
    *(uint4*)(&Ks[0][(srow + 32) * 72 + sseg * 8]) = kreg1;
    *(uint4*)(&Vs[0][(srow)      * 72 + sseg * 8]) = vreg0;
    *(uint4*)(&Vs[0][(srow + 32) * 72 + sseg * 8]) = vreg1;
    kreg0 = *(const uint4*)(&kh[(size_t)(64 + srow)      * DH + sseg * 8]);
    kreg1 = *(const uint4*)(&kh[(size_t)(64 + srow + 32) * DH + sseg * 8]);
    vreg0 = *(const uint4*)(&vh[(size_t)(srow)      * S_LEN + 64 + sseg * 8]);
    vreg1 = *(const uint4*)(&vh[(size_t)(srow + 32) * S_LEN + 64 + sseg * 8]);
    __syncthreads();

    for (int it = 0; it < 32; it++) {
        const int cur = it & 1;
        const unsigned short* Kc = &Ks[cur][0];
        const unsigned short* Vc = &Vs[cur][0];
        if (it < 31) {
            unsigned short* Kn = &Ks[cur ^ 1][0];
            unsigned short* Vn = &Vs[cur ^ 1][0];
            *(uint4*)(&Kn[(srow)      * 72 + sseg * 8]) = kreg0;
            *(uint4*)(&Kn[(srow + 32) * 72 + sseg * 8]) = kreg1;
            *(uint4*)(&Vn[(srow)      * 72 + sseg * 8]) = vreg0;
            *(uint4*)(&Vn[(srow + 32) * 72 + sseg * 8]) = vreg1;
        }
        if (it < 30) {
            const int kn = (it + 2) * 64;
            kreg0 = *(const uint4*)(&kh[(size_t)(kn + srow)      * DH + sseg * 8]);
            kreg1 = *(const uint4*)(&kh[(size_t)(kn + srow + 32) * DH + sseg * 8]);
            vreg0 = *(const uint4*)(&vh[(size_t)(srow)      * S_LEN + kn + sseg * 8]);
            vreg1 = *(const uint4*)(&vh[(size_t)(srow + 32) * S_LEN + kn + sseg * 8]);
        }

        const uint2 mwA = *(const uint2*)(&mrA[it * 2]);
        const uint2 mwB = *(const uint2*)(&mrB[it * 2]);

        // S^T tiles: D[row=kv_loc=lg*4+r][col=q=lr], kv = it*64+ni*16+lg*4+r.
        f32x4 sA[4], sB[4];
        __builtin_amdgcn_s_setprio(1);
#pragma unroll
        for (int ni = 0; ni < 4; ni++) {
            bf16x8 ak0 = *(const bf16x8*)(&Kc[(ni * 16 + lr) * 72 + lg * 8]);
            bf16x8 ak1 = *(const bf16x8*)(&Kc[(ni * 16 + lr) * 72 + 32 + lg * 8]);
            f32x4 tA = __builtin_amdgcn_mfma_f32_16x16x32_bf16(ak0, aqA[0], f32x4{0.f,0.f,0.f,0.f}, 0,0,0);
            tA = __builtin_amdgcn_mfma_f32_16x16x32_bf16(ak1, aqA[1], tA, 0,0,0);
            f32x4 tB = __builtin_amdgcn_mfma_f32_16x16x32_bf16(ak0, aqB[0], f32x4{0.f,0.f,0.f,0.f}, 0,0,0);
            tB = __builtin_amdgcn_mfma_f32_16x16x32_bf16(ak1, aqB[1], tB, 0,0,0);
            sA[ni] = tA; sB[ni] = tB;
        }
        __builtin_amdgcn_s_setprio(0);

        // Softmax numerator: p = masked ? 0 : exp2(s)  (s pre-scaled in Q).
#pragma unroll
        for (int ni = 0; ni < 4; ni++) {
            unsigned wA = (ni & 2) ? mwA.y : mwA.x;
            unsigned wB = (ni & 2) ? mwB.y : mwB.x;
            unsigned nibA = wA >> ((ni & 1) * 16 + lg * 4);
            unsigned nibB = wB >> ((ni & 1) * 16 + lg * 4);
#pragma unroll
            for (int r = 0; r < 4; r++) {
                float pA = exp2_hw(sA[ni][r]);
                float pB = exp2_hw(sB[ni][r]);
                sA[ni][r] = (nibA & (1u << r)) ? 0.f : pA;
                sB[ni][r] = (nibB & (1u << r)) ? 0.f : pB;
            }
        }

        // Native P -> bf16x4 B-operands per 16-kv chunk (plain casts ->
        // v_cvt_pk_bf16_f32 pairs). Lane (lr,lg) holds P^T[16ni+4lg+r][lr],
        // which IS the K=16 MFMA B layout (col=lr, k=4lg+r). No transpose.
        bf16x4 bpA[4], bpB[4];
#pragma unroll
        for (int ni = 0; ni < 4; ni++) {
#pragma unroll
            for (int r = 0; r < 4; r++) {
                bpA[ni][r] = (__bf16)sA[ni][r];
                bpB[ni][r] = (__bf16)sB[ni][r];
            }
        }

        // O^T += V^T * P^T via K=16 MFMAs; A = V^T[dh=di*16+lr][16ni+4lg+j]
        // (ds_read_b64 slices). Row sums on the matrix pipe.
        __builtin_amdgcn_s_setprio(1);
#pragma unroll
        for (int di = 0; di < 4; di++) {
#pragma unroll
            for (int ni = 0; ni < 4; ni++) {
                bf16x4 av = *(const bf16x4*)(&Vc[(di * 16 + lr) * 72 + ni * 16 + lg * 4]);
                accA[di] = mfma16(av, bpA[ni], accA[di]);
                accB[di] = mfma16(av, bpB[ni], accB[di]);
            }
        }
#pragma unroll
        for (int ni = 0; ni < 4; ni++) {
            accRA = mfma16(ones4, bpA[ni], accRA);
            accRB = mfma16(ones4, bpB[ni], accRB);
        }
        __builtin_amdgcn_s_setprio(0);

        __syncthreads();
    }

    const float invA = 1.0f / fmaxf(accRA[0], 1e-37f);
    const float invB = 1.0f / fmaxf(accRB[0], 1e-37f);

    unsigned short* crowA = &ctx[((size_t)(b * S_LEN + qA)) * DM + h * DH];
    unsigned short* crowB = &ctx[((size_t)(b * S_LEN + qB)) * DM + h * DH];
#pragma unroll
    for (int di = 0; di < 4; di++) {
        bf16x4 oA, oB;
#pragma unroll
        for (int r = 0; r < 4; r++) {
            oA[r] = (__bf16)(accA[di][r] * invA);
            oB[r] = (__bf16)(accB[di][r] * invB);
        }
        *(bf16x4*)(&crowA[di * 16 + lg * 4]) = oA;
        *(bf16x4*)(&crowB[di * 16 + lg * 4]) = oB;
    }
}

extern "C" void kernel_launch(void* const* d_in, const int* in_sizes, int n_in,
                              void* d_out, int out_size, void* d_ws, size_t ws_size,
                              hipStream_t stream)
{
    (void)in_sizes; (void)n_in; (void)out_size; (void)ws_size;
    const float* Q  = (const float*)d_in[0];
    const float* K  = (const float*)d_in[1];
    const float* V  = (const float*)d_in[2];
    const int*   Mk = (const int*)d_in[3];
    const float* Wq = (const float*)d_in[4];
    const float* bq = (const float*)d_in[5];
    const float* Wk = (const float*)d_in[6];
    const float* bk = (const float*)d_in[7];
    const float* Wv = (const float*)d_in[8];
    const float* bv = (const float*)d_in[9];
    const float* Wo = (const float*)d_in[10];
    const float* bo = (const float*)d_in[11];

    const int NX = MROWS * DM;   // 4194304
    const int NW = DM * DM;      // 1048576

    unsigned short* q_ws  = (unsigned short*)d_ws;
    unsigned short* k_ws  = q_ws + (size_t)NX;
    unsigned short* vt_ws = k_ws + (size_t)NX;
    unsigned short* ctx   = vt_ws + (size_t)NX;
    unsigned*       mbits = (unsigned*)(ctx + (size_t)NX);
    unsigned short* Wbq   = (unsigned short*)(mbits + (size_t)MROWS * (S_LEN / 32));
    unsigned short* Wbk   = Wbq + (size_t)NW;
    unsigned short* Wbv   = Wbk + (size_t)NW;
    unsigned short* Wbo   = Wbv + (size_t)NW;
    unsigned short* Xbq   = Wbo + (size_t)NW;
    unsigned short* Xbk   = Xbq + (size_t)NX;
    unsigned short* Xbv   = Xbk + (size_t)NX;
    float* out = (float*)d_out;

    dim3 blk(256);
    prep<<<dim3(9216), blk, 0, stream>>>(Mk, mbits, Q, Xbq, K, Xbk, V, Xbv,
                                         Wq, Wbq, Wk, Wbk, Wv, Wbv, Wo, Wbo);

    gemm128<<<dim3(8, 32, 3), blk, 0, stream>>>(Xbq, Xbk, Xbv, Wbq, Wbk, Wbv,
                                                bq, bk, bv, q_ws, k_ws, vt_ws);

    attn<<<dim3(512), blk, 0, stream>>>(q_ws, k_ws, vt_ws, mbits, ctx);

    gemm_out<<<dim3(16, 32), blk, 0, stream>>>(ctx, Wbo, bo, out);
}

// Round 7
// 259.845 us; speedup vs baseline: 1.0514x; 1.0514x over previous
//
#include <hip/hip_runtime.h>
#include <hip/hip_bf16.h>

// B=2, S=2048, D_MODEL=1024, H=16, D_HEAD=64.
// I/O fp32; mask int32 (nonzero = masked). Internals bf16 MFMA.
// R17: best-of config. gemms reverted to R13 single-buffer form (R15 dbuf
// cost ~7us; syncthreads drains vmcnt regardless). attn = R15 (K=32 MFMA +
// verified permlane P^T butterfly; R16's K=16 path regressed: 2x MFMA instrs
// at half FLOP each) + KVBLK=128 processed as two 64-halves per barrier:
// barriers 32->16, staging clusters halved. LDS 71.7KB, 2 blocks/CU.

typedef __bf16 bf16x8 __attribute__((ext_vector_type(8)));
typedef __bf16 bf16x4 __attribute__((ext_vector_type(4)));
typedef float f32x4 __attribute__((ext_vector_type(4)));

#define S_LEN 2048
#define DM 1024
#define NH 16
#define DH 64
#define MROWS 4096  // B*S

// 0.125 * log2(e): folds the 1/sqrt(DH) scale AND the exp->exp2 base change
// into the Q projection (applied in f32 before the single bf16 rounding).
#define QSCALE 0.18033688011112042f

static __device__ __forceinline__ unsigned short f2bf(float f) {
    __bf16 b = (__bf16)f;
    unsigned short u; __builtin_memcpy(&u, &b, 2); return u;
}

static __device__ __forceinline__ float exp2_hw(float x) {
#if __has_builtin(__builtin_amdgcn_exp2f)
    return __builtin_amdgcn_exp2f(x);
#else
    float r; asm("v_exp_f32 %0, %1" : "=v"(r) : "v"(x)); return r;
#endif
}

// dst.lo16 = bf16(lo), dst.hi16 = bf16(hi)  (RNE, same numerics as (__bf16))
static __device__ __forceinline__ unsigned cvtpk_bf16(float lo, float hi) {
    unsigned r;
    asm("v_cvt_pk_bf16_f32 %0, %1, %2" : "=v"(r) : "v"(lo), "v"(hi));
    return r;
}
// x'[32..63]=y[0..31]; y'[0..31]=x[32..63]
static __device__ __forceinline__ void pl32swap(unsigned &x, unsigned &y) {
    asm volatile("v_permlane32_swap_b32 %0, %1" : "+v"(x), "+v"(y));
}
// within each 32-lane half: x'[16..31]=y[0..15]; y'[0..15]=x[16..31]
static __device__ __forceinline__ void pl16swap(unsigned &x, unsigned &y) {
    asm volatile("v_permlane16_swap_b32 %0, %1" : "+v"(x), "+v"(y));
}

static __device__ __forceinline__ bf16x8 cvt8(float4 a, float4 b) {
    bf16x8 o;
    o[0] = (__bf16)a.x; o[1] = (__bf16)a.y; o[2] = (__bf16)a.z; o[3] = (__bf16)a.w;
    o[4] = (__bf16)b.x; o[5] = (__bf16)b.y; o[6] = (__bf16)b.z; o[7] = (__bf16)b.w;
    return o;
}

// Fused prep: mask bit-pack + 3 X cvts + 4 W cvts in one launch.
__global__ __launch_bounds__(256)
void prep(const int* __restrict__ m, unsigned* __restrict__ mb,
          const float* __restrict__ Q, unsigned short* __restrict__ dQ,
          const float* __restrict__ K, unsigned short* __restrict__ dK,
          const float* __restrict__ V, unsigned short* __restrict__ dV,
          const float* __restrict__ W0, unsigned short* __restrict__ dW0,
          const float* __restrict__ W1, unsigned short* __restrict__ dW1,
          const float* __restrict__ W2, unsigned short* __restrict__ dW2,
          const float* __restrict__ W3, unsigned short* __restrict__ dW3)
{
    const int bx = blockIdx.x, tid = threadIdx.x;
    if (bx < 1024) {
        const int lane = tid & 63, w = tid >> 6;
        const int row = bx * 4 + w;
        const int* src = m + (size_t)row * S_LEN;
        unsigned* dst = mb + (size_t)row * (S_LEN / 32);
        for (int i = 0; i < 32; i++) {
            int v = src[i * 64 + lane];
            unsigned long long bm = __ballot(v != 0);
            if (lane == 0) { dst[i*2] = (unsigned)bm; dst[i*2+1] = (unsigned)(bm >> 32); }
        }
    } else if (bx < 7168) {
        int t = bx - 1024;
        int which = t >> 11;
        const float* s = which == 0 ? Q : which == 1 ? K : V;
        unsigned short* d = which == 0 ? dQ : which == 1 ? dK : dV;
        int i = ((t & 2047) * 256 + tid) * 8;
        float4 a = *(const float4*)(s + i);
        float4 b = *(const float4*)(s + i + 4);
        *(bf16x8*)(d + i) = cvt8(a, b);
    } else {
        int t = bx - 7168;
        int which = t >> 9;
        const float* s = which == 0 ? W0 : which == 1 ? W1 : which == 2 ? W2 : W3;
        unsigned short* d = which == 0 ? dW0 : which == 1 ? dW1 : which == 2 ? dW2 : dW3;
        int i = ((t & 511) * 256 + tid) * 8;
        float4 a = *(const float4*)(s + i);
        float4 b = *(const float4*)(s + i + 4);
        *(bf16x8*)(d + i) = cvt8(a, b);
    }
}

// m97-style GEMM for QKV: 128x128 tile, BK=32, global_load_lds. z = mode:
// 0/1: head-split bf16 (q_ws/k_ws); 2: transposed bf16 (vt_ws).
// z==0 (Q) epilogue pre-scales by QSCALE. XCD chunk swizzle: each XCD owns
// (all 8 n-tiles x 4 m-tiles) per z -> 3MB working set per XCD L2.
__global__ __launch_bounds__(256)
void gemm128(const unsigned short* __restrict__ X0, const unsigned short* __restrict__ X1,
             const unsigned short* __restrict__ X2,
             const unsigned short* __restrict__ W0, const unsigned short* __restrict__ W1,
             const unsigned short* __restrict__ W2,
             const float* __restrict__ b0, const float* __restrict__ b1,
             const float* __restrict__ b2,
             unsigned short* __restrict__ d0, unsigned short* __restrict__ d1,
             unsigned short* __restrict__ d2)
{
    __shared__ __align__(16) unsigned short As[128 * 32];
    __shared__ __align__(16) unsigned short Bs[128 * 32];

    const int bid = blockIdx.x + blockIdx.y * 8 + blockIdx.z * 256; // 0..767
    const int xcd = bid & 7;
    const int t   = bid >> 3;
    const int z   = t >> 5;
    const int u   = t & 31;
    const int nt  = u & 7;
    const int mt  = xcd * 4 + (u >> 3);

    const unsigned short* X = z == 0 ? X0 : z == 1 ? X1 : X2;
    const unsigned short* W = z == 0 ? W0 : z == 1 ? W1 : W2;
    const float* bias        = z == 0 ? b0 : z == 1 ? b1 : b2;
    unsigned short* dstb     = z == 0 ? d0 : z == 1 ? d1 : d2;

    const int tid  = threadIdx.x;
    const int m0   = mt * 128;
    const int n0   = nt * 128;
    const int lane = tid & 63;
    const int w    = tid >> 6;
    const int wm   = (w >> 1) * 64, wn = (w & 1) * 64;
    const int lr   = lane & 15;
    const int lg   = lane >> 4;

    f32x4 acc[4][4];
#pragma unroll
    for (int i = 0; i < 4; i++)
#pragma unroll
        for (int j = 0; j < 4; j++) acc[i][j] = f32x4{0.f, 0.f, 0.f, 0.f};

    for (int k0 = 0; k0 < DM; k0 += 32) {
        __syncthreads();
#pragma unroll
        for (int j = 0; j < 2; j++) {
            int e = tid + j * 256;
            int row = e >> 2, c8 = (e & 3) * 8;
            __builtin_amdgcn_global_load_lds(
                (const __attribute__((address_space(1))) unsigned*)&X[(size_t)(m0 + row) * DM + k0 + c8],
                (__attribute__((address_space(3))) unsigned*)&As[e * 8], 16, 0, 0);
            __builtin_amdgcn_global_load_lds(
                (const __attribute__((address_space(1))) unsigned*)&W[(size_t)(n0 + row) * DM + k0 + c8],
                (__attribute__((address_space(3))) unsigned*)&Bs[e * 8], 16, 0, 0);
        }
        __syncthreads();
        bf16x8 af[4], bfr[4];
#pragma unroll
        for (int mi = 0; mi < 4; mi++)
            af[mi] = *(const bf16x8*)(&As[(wm + mi * 16 + lr) * 32 + lg * 8]);
#pragma unroll
        for (int ni = 0; ni < 4; ni++)
            bfr[ni] = *(const bf16x8*)(&Bs[(wn + ni * 16 + lr) * 32 + lg * 8]);
#pragma unroll
        for (int mi = 0; mi < 4; mi++)
#pragma unroll
            for (int ni = 0; ni < 4; ni++)
                acc[mi][ni] = __builtin_amdgcn_mfma_f32_16x16x32_bf16(
                    af[mi], bfr[ni], acc[mi][ni], 0, 0, 0);
    }

    // C/D layout: col = lane&15 -> n, row = (lane>>4)*4 + reg -> m.
#pragma unroll
    for (int mi = 0; mi < 4; mi++) {
#pragma unroll
        for (int ni = 0; ni < 4; ni++) {
            const int gcol = n0 + wn + ni * 16 + lr;
            const float bv = bias[gcol];
            const int grow0 = m0 + wm + mi * 16 + lg * 4;
            if (z == 2) {
                int b = grow0 >> 11, s = grow0 & (S_LEN - 1);
                int h = gcol >> 6, dh = gcol & 63;
                bf16x4 pk;
#pragma unroll
                for (int r = 0; r < 4; r++) pk[r] = (__bf16)(acc[mi][ni][r] + bv);
                size_t di = ((size_t)(b * NH + h) * DH + dh) * S_LEN + s;
                *(bf16x4*)(&dstb[di]) = pk;
            } else {
#pragma unroll
                for (int r = 0; r < 4; r++) {
                    int grow = grow0 + r;
                    float v = acc[mi][ni][r] + bv;
                    if (z == 0) v *= QSCALE;
                    int b = grow >> 11, s = grow & (S_LEN - 1);
                    int h = gcol >> 6, dh = gcol & 63;
                    dstb[((size_t)(b * NH + h) * S_LEN + s) * DH + dh] = f2bf(v);
                }
            }
        }
    }
}

// Out-projection: Y = X @ Wo^T + bo, fp32 out. 128M x 64N tiles, 512 blocks,
// XCD chunk swizzle (16 n-tiles x 4 m-tiles/XCD).
__global__ __launch_bounds__(256, 4)
void gemm_out(const unsigned short* __restrict__ X, const unsigned short* __restrict__ W,
              const float* __restrict__ bias, float* __restrict__ dst)
{
    __shared__ __align__(16) unsigned short As[128 * 32];
    __shared__ __align__(16) unsigned short Bs[64 * 32];

    const int bid = blockIdx.x + blockIdx.y * 16; // 0..511
    const int xcd = bid & 7;
    const int u   = bid >> 3;
    const int nt  = u & 15;
    const int mt  = xcd * 4 + (u >> 4);

    const int tid  = threadIdx.x;
    const int m0   = mt * 128;
    const int n0   = nt * 64;
    const int lane = tid & 63;
    const int w    = tid >> 6;
    const int wm   = (w >> 1) * 64, wn = (w & 1) * 32;
    const int lr   = lane & 15;
    const int lg   = lane >> 4;

    f32x4 acc[4][2];
#pragma unroll
    for (int i = 0; i < 4; i++)
#pragma unroll
        for (int j = 0; j < 2; j++) acc[i][j] = f32x4{0.f, 0.f, 0.f, 0.f};

    for (int k0 = 0; k0 < DM; k0 += 32) {
        __syncthreads();
#pragma unroll
        for (int j = 0; j < 2; j++) {
            int e = tid + j * 256;
            int row = e >> 2, c8 = (e & 3) * 8;
            __builtin_amdgcn_global_load_lds(
                (const __attribute__((address_space(1))) unsigned*)&X[(size_t)(m0 + row) * DM + k0 + c8],
                (__attribute__((address_space(3))) unsigned*)&As[e * 8], 16, 0, 0);
        }
        {
            int row = tid >> 2, c8 = (tid & 3) * 8;
            __builtin_amdgcn_global_load_lds(
                (const __attribute__((address_space(1))) unsigned*)&W[(size_t)(n0 + row) * DM + k0 + c8],
                (__attribute__((address_space(3))) unsigned*)&Bs[tid * 8], 16, 0, 0);
        }
        __syncthreads();
        bf16x8 af[4], bfr[2];
#pragma unroll
        for (int mi = 0; mi < 4; mi++)
            af[mi] = *(const bf16x8*)(&As[(wm + mi * 16 + lr) * 32 + lg * 8]);
#pragma unroll
        for (int ni = 0; ni < 2; ni++)
            bfr[ni] = *(const bf16x8*)(&Bs[(wn + ni * 16 + lr) * 32 + lg * 8]);
#pragma unroll
        for (int mi = 0; mi < 4; mi++)
#pragma unroll
            for (int ni = 0; ni < 2; ni++)
                acc[mi][ni] = __builtin_amdgcn_mfma_f32_16x16x32_bf16(
                    af[mi], bfr[ni], acc[mi][ni], 0, 0, 0);
    }
#pragma unroll
    for (int mi = 0; mi < 4; mi++)
#pragma unroll
        for (int ni = 0; ni < 2; ni++) {
            const int gcol = n0 + wn + ni * 16 + lr;
            const float bv = bias[gcol];
            const int grow0 = m0 + wm + mi * 16 + lg * 4;
#pragma unroll
            for (int r = 0; r < 4; r++)
                dst[(size_t)(grow0 + r) * DM + gcol] = acc[mi][ni][r] + bv;
        }
}

// Flash attention (transposed): S^T = K*Q^T, softmax rows along lanes.
// Wave owns 2 q-tiles (32 q). KVBLK=128, double-buffered, processed as two
// 64-halves per barrier (16 barriers total). P^T in-register via cvt_pk +
// permlane butterfly. Row-sum via ones-MFMA. Grid 512 (XCD swizzle).
__global__ __launch_bounds__(256, 2)
void attn(const unsigned short* __restrict__ q_ws,
          const unsigned short* __restrict__ k_ws,
          const unsigned short* __restrict__ vt_ws,
          const unsigned* __restrict__ mbits,
          unsigned short* __restrict__ ctx)
{
    __shared__ __align__(16) unsigned short Ks[2][128 * 72];   // [kv][dh], +8 pad
    __shared__ __align__(16) unsigned short Vs[2][64 * 136];   // [dh][kv], +8 pad
    const int tid = threadIdx.x, lane = tid & 63, w = tid >> 6;
    const int lr = lane & 15, lg = lane >> 4;

    const int i    = blockIdx.x;            // 0..511
    const int xcd  = i & 7;
    const int slot = i >> 3;                // 0..63
    const int bh   = xcd * 4 + (slot >> 4); // 4 bh per XCD (K/V L2-resident)
    const int qblk = slot & 15;
    const int b  = bh >> 4;
    const int h  = bh & 15;
    const int q0 = qblk * 128 + w * 32;
    const int qA = q0 + lr;
    const int qB = q0 + 16 + lr;

    const int krow = tid >> 3, kseg = tid & 7;   // K stage: rows krow+32j
    const int vrow = tid >> 4, vseg = tid & 15;  // V stage: rows vrow+16j

    const unsigned short* qh = q_ws + (size_t)bh * S_LEN * DH;
    const unsigned short* kh = k_ws + (size_t)bh * S_LEN * DH;
    const unsigned short* vh = vt_ws + (size_t)bh * DH * S_LEN;
    const unsigned* mrA = mbits + (size_t)(b * S_LEN + qA) * (S_LEN / 32);
    const unsigned* mrB = mbits + (size_t)(b * S_LEN + qB) * (S_LEN / 32);

    // Q fragments (B operand of K*Q^T): Q[q][dh = c*32 + lg*8 + j].
    bf16x8 aqA[2], aqB[2];
#pragma unroll
    for (int c = 0; c < 2; c++) {
        aqA[c] = *(const bf16x8*)(&qh[(size_t)qA * DH + c * 32 + lg * 8]);
        aqB[c] = *(const bf16x8*)(&qh[(size_t)qB * DH + c * 32 + lg * 8]);
    }

    bf16x8 ones;
#pragma unroll
    for (int j = 0; j < 8; j++) ones[j] = (__bf16)1.0f;

    f32x4 accA[4], accB[4], accRA, accRB;
#pragma unroll
    for (int di = 0; di < 4; di++) {
        accA[di] = f32x4{0.f, 0.f, 0.f, 0.f};
        accB[di] = f32x4{0.f, 0.f, 0.f, 0.f};
    }
    accRA = f32x4{0.f, 0.f, 0.f, 0.f};
    accRB = f32x4{0.f, 0.f, 0.f, 0.f};

    uint4 kr0, kr1, kr2, kr3, vr0, vr1, vr2, vr3;

#define LOADSTAGE(kv0)                                                               \
    do {                                                                             \
        kr0 = *(const uint4*)(&kh[(size_t)((kv0) + krow)      * DH + kseg * 8]);     \
        kr1 = *(const uint4*)(&kh[(size_t)((kv0) + krow + 32) * DH + kseg * 8]);     \
        kr2 = *(const uint4*)(&kh[(size_t)((kv0) + krow + 64) * DH + kseg * 8]);     \
        kr3 = *(const uint4*)(&kh[(size_t)((kv0) + krow + 96) * DH + kseg * 8]);     \
        vr0 = *(const uint4*)(&vh[(size_t)(vrow)      * S_LEN + (kv0) + vseg * 8]);  \
        vr1 = *(const uint4*)(&vh[(size_t)(vrow + 16) * S_LEN + (kv0) + vseg * 8]);  \
        vr2 = *(const uint4*)(&vh[(size_t)(vrow + 32) * S_LEN + (kv0) + vseg * 8]);  \
        vr3 = *(const uint4*)(&vh[(size_t)(vrow + 48) * S_LEN + (kv0) + vseg * 8]);  \
    } while (0)

#define WRITESTAGE(buf)                                                              \
    do {                                                                             \
        *(uint4*)(&Ks[buf][(krow)      * 72 + kseg * 8]) = kr0;                      \
        *(uint4*)(&Ks[buf][(krow + 32) * 72 + kseg * 8]) = kr1;                      \
        *(uint4*)(&Ks[buf][(krow + 64) * 72 + kseg * 8]) = kr2;                      \
        *(uint4*)(&Ks[buf][(krow + 96) * 72 + kseg * 8]) = kr3;                      \
        *(uint4*)(&Vs[buf][(vrow)      * 136 + vseg * 8]) = vr0;                     \
        *(uint4*)(&Vs[buf][(vrow + 16) * 136 + vseg * 8]) = vr1;                     \
        *(uint4*)(&Vs[buf][(vrow + 32) * 136 + vseg * 8]) = vr2;                     \
        *(uint4*)(&Vs[buf][(vrow + 48) * 136 + vseg * 8]) = vr3;                     \
    } while (0)

    LOADSTAGE(0);
    WRITESTAGE(0);
    LOADSTAGE(128);
    __syncthreads();

    for (int it = 0; it < 16; it++) {
        const int cur = it & 1;
        if (it < 15) WRITESTAGE(cur ^ 1);     // tile it+1 (prev readers done)
        if (it < 14) LOADSTAGE((it + 2) * 128);

        const uint4 mA = *(const uint4*)(&mrA[it * 4]);
        const uint4 mB = *(const uint4*)(&mrB[it * 4]);

#pragma unroll
        for (int hb = 0; hb < 2; hb++) {
            const unsigned short* Kc = &Ks[cur][hb * 64 * 72];
            const unsigned short* Vc = &Vs[cur][hb * 64];
            const unsigned mwAx = hb ? mA.z : mA.x;
            const unsigned mwAy = hb ? mA.w : mA.y;
            const unsigned mwBx = hb ? mB.z : mB.x;
            const unsigned mwBy = hb ? mB.w : mB.y;

            // S^T tiles: D[row=kv_loc=lg*4+r][col=q=lr].
            f32x4 sA[4], sB[4];
            __builtin_amdgcn_s_setprio(1);
#pragma unroll
            for (int ni = 0; ni < 4; ni++) {
                bf16x8 ak0 = *(const bf16x8*)(&Kc[(ni * 16 + lr) * 72 + lg * 8]);
                bf16x8 ak1 = *(const bf16x8*)(&Kc[(ni * 16 + lr) * 72 + 32 + lg * 8]);
                f32x4 tA = __builtin_amdgcn_mfma_f32_16x16x32_bf16(ak0, aqA[0], f32x4{0.f,0.f,0.f,0.f}, 0,0,0);
                tA = __builtin_amdgcn_mfma_f32_16x16x32_bf16(ak1, aqA[1], tA, 0,0,0);
                f32x4 tB = __builtin_amdgcn_mfma_f32_16x16x32_bf16(ak0, aqB[0], f32x4{0.f,0.f,0.f,0.f}, 0,0,0);
                tB = __builtin_amdgcn_mfma_f32_16x16x32_bf16(ak1, aqB[1], tB, 0,0,0);
                sA[ni] = tA; sB[ni] = tB;
            }
            __builtin_amdgcn_s_setprio(0);

            // Softmax numerator: p = masked ? 0 : exp2(s).
#pragma unroll
            for (int ni = 0; ni < 4; ni++) {
                unsigned wA = (ni & 2) ? mwAy : mwAx;
                unsigned wB = (ni & 2) ? mwBy : mwBx;
                unsigned nibA = wA >> ((ni & 1) * 16 + lg * 4);
                unsigned nibB = wB >> ((ni & 1) * 16 + lg * 4);
#pragma unroll
                for (int r = 0; r < 4; r++) {
                    float pA = exp2_hw(sA[ni][r]);
                    float pB = exp2_hw(sB[ni][r]);
                    sA[ni][r] = (nibA & (1u << r)) ? 0.f : pA;
                    sB[ni][r] = (nibB & (1u << r)) ? 0.f : pB;
                }
            }

            // In-register P^T: cvt_pk pairs + 2-stage permlane butterfly
            // (verified R14/R15): lane (lr,g) ends with P[q=lr][kv=32c+8g+j].
            unsigned wpA[8], wpB[8];
#pragma unroll
            for (int ni = 0; ni < 4; ni++) {
                wpA[ni*2]   = cvtpk_bf16(sA[ni][0], sA[ni][1]);
                wpA[ni*2+1] = cvtpk_bf16(sA[ni][2], sA[ni][3]);
                wpB[ni*2]   = cvtpk_bf16(sB[ni][0], sB[ni][1]);
                wpB[ni*2+1] = cvtpk_bf16(sB[ni][2], sB[ni][3]);
            }
#pragma unroll
            for (int c = 0; c < 2; c++) {
                pl32swap(wpA[c*4 + 0], wpA[c*4 + 2]);
                pl32swap(wpA[c*4 + 1], wpA[c*4 + 3]);
                pl16swap(wpA[c*4 + 0], wpA[c*4 + 2]);
                pl16swap(wpA[c*4 + 1], wpA[c*4 + 3]);
                pl32swap(wpB[c*4 + 0], wpB[c*4 + 2]);
                pl32swap(wpB[c*4 + 1], wpB[c*4 + 3]);
                pl16swap(wpB[c*4 + 0], wpB[c*4 + 2]);
                pl16swap(wpB[c*4 + 1], wpB[c*4 + 3]);
            }
            bf16x8 bpA0, bpA1, bpB0, bpB1;
            __builtin_memcpy(&bpA0, &wpA[0], 16);
            __builtin_memcpy(&bpA1, &wpA[4], 16);
            __builtin_memcpy(&bpB0, &wpB[0], 16);
            __builtin_memcpy(&bpB1, &wpB[4], 16);

            // O^T += V^T * P^T; row sums on the matrix pipe.
            __builtin_amdgcn_s_setprio(1);
#pragma unroll
            for (int di = 0; di < 4; di++) {
                bf16x8 av0 = *(const bf16x8*)(&Vc[(di * 16 + lr) * 136 + lg * 8]);
                bf16x8 av1 = *(const bf16x8*)(&Vc[(di * 16 + lr) * 136 + 32 + lg * 8]);
                accA[di] = __builtin_amdgcn_mfma_f32_16x16x32_bf16(av0, bpA0, accA[di], 0, 0, 0);
                accA[di] = __builtin_amdgcn_mfma_f32_16x16x32_bf16(av1, bpA1, accA[di], 0, 0, 0);
                accB[di] = __builtin_amdgcn_mfma_f32_16x16x32_bf16(av0, bpB0, accB[di], 0, 0, 0);
                accB[di] = __builtin_amdgcn_mfma_f32_16x16x32_bf16(av1, bpB1, accB[di], 0, 0, 0);
            }
            accRA = __builtin_amdgcn_mfma_f32_16x16x32_bf16(ones, bpA0, accRA, 0, 0, 0);
            accRA = __builtin_amdgcn_mfma_f32_16x16x32_bf16(ones, bpA1, accRA, 0, 0, 0);
            accRB = __builtin_amdgcn_mfma_f32_16x16x32_bf16(ones, bpB0, accRB, 0, 0, 0);
            accRB = __builtin_amdgcn_mfma_f32_16x16x32_bf16(ones, bpB1, accRB, 0, 0, 0);
            __builtin_amdgcn_s_setprio(0);
        }

        __syncthreads();
    }
#undef LOADSTAGE
#undef WRITESTAGE

    const float invA = 1.0f / fmaxf(accRA[0], 1e-37f);
    const float invB = 1.0f / fmaxf(accRB[0], 1e-37f);

    unsigned short* crowA = &ctx[((size_t)(b * S_LEN + qA)) * DM + h * DH];
    unsigned short* crowB = &ctx[((size_t)(b * S_LEN + qB)) * DM + h * DH];
#pragma unroll
    for (int di = 0; di < 4; di++) {
        bf16x4 oA, oB;
#pragma unroll
        for (int r = 0; r < 4; r++) {
            oA[r] = (__bf16)(accA[di][r] * invA);
            oB[r] = (__bf16)(accB[di][r] * invB);
        }
        *(bf16x4*)(&crowA[di * 16 + lg * 4]) = oA;
        *(bf16x4*)(&crowB[di * 16 + lg * 4]) = oB;
    }
}

extern "C" void kernel_launch(void* const* d_in, const int* in_sizes, int n_in,
                              void* d_out, int out_size, void* d_ws, size_t ws_size,
                              hipStream_t stream)
{
    (void)in_sizes; (void)n_in; (void)out_size; (void)ws_size;
    const float* Q  = (const float*)d_in[0];
    const float* K  = (const float*)d_in[1];
    const float* V  = (const float*)d_in[2];
    const int*   Mk = (const int*)d_in[3];
    const float* Wq = (const float*)d_in[4];
    const float* bq = (const float*)d_in[5];
    const float* Wk = (const float*)d_in[6];
    const float* bk = (const float*)d_in[7];
    const float* Wv = (const float*)d_in[8];
    const float* bv = (const float*)d_in[9];
    const float* Wo = (const float*)d_in[10];
    const float* bo = (const float*)d_in[11];

    const int NX = MROWS * DM;   // 4194304
    const int NW = DM * DM;      // 1048576

    unsigned short* q_ws  = (unsigned short*)d_ws;
    unsigned short* k_ws  = q_ws + (size_t)NX;
    unsigned short* vt_ws = k_ws + (size_t)NX;
    unsigned short* ctx   = vt_ws + (size_t)NX;
    unsigned*       mbits = (unsigned*)(ctx + (size_t)NX);
    unsigned short* Wbq   = (unsigned short*)(mbits + (size_t)MROWS * (S_LEN / 32));
    unsigned short* Wbk   = Wbq + (size_t)NW;
    unsigned short* Wbv   = Wbk + (size_t)NW;
    unsigned short* Wbo   = Wbv + (size_t)NW;
    unsigned short* Xbq   = Wbo + (size_t)NW;
    unsigned short* Xbk   = Xbq + (size_t)NX;
    unsigned short* Xbv   = Xbk + (size_t)NX;
    float* out = (float*)d_out;

    dim3 blk(256);
    prep<<<dim3(9216), blk, 0, stream>>>(Mk, mbits, Q, Xbq, K, Xbk, V, Xbv,
                                         Wq, Wbq, Wk, Wbk, Wv, Wbv, Wo, Wbo);

    gemm128<<<dim3(8, 32, 3), blk, 0, stream>>>(Xbq, Xbk, Xbv, Wbq, Wbk, Wbv,
                                                bq, bk, bv, q_ws, k_ws, vt_ws);

    attn<<<dim3(512), blk, 0, stream>>>(q_ws, k_ws, vt_ws, mbits, ctx);

    gemm_out<<<dim3(16, 32), blk, 0, stream>>>(ctx, Wbo, bo, out);
}